// Round 11
// baseline (330.478 us; speedup 1.0000x reference)
//
#include <hip/hip_runtime.h>

// LSTM B=4096, T=512, I=2, H=50, O=3 — MFMA bf16x3, round 11.
// vs r10 (identical structure otherwise):
//  * x-writer moved to TOP of t-body: writes x(t+1) right after barrier
//    release, then issues the x(t+2) global load -> the pre-barrier
//    s_waitcnt vmcnt(0) drain now has a full body of shadow instead of 0.
//    (r7/r9/r10's invariant ~1600cyc/t wall = x-writer stalled at every
//    barrier on a zero-shadow global load, pacing the whole block.)
//  * 6-MFMA accumulation split into 3 independent 2-chains.
//   A (M) = weight rows, m = 4*u_local + gate  (VGPR frags, tile tau = wave)
//   B (N) = h, n = batch row                   (4x ds_read_b128, broadcast)
//   C: col=lane&15=batch, grp=lane>>4=unit-in-tile, reg=GATE
// K carries everything: k<50 h, k=50/51 x0/x1, k=52 bias (const 1.0).
// Waves 0..12 active, wave 13 = x-writer, 14/15 barrier-only. ONE barrier/t.

typedef short bf16x8 __attribute__((ext_vector_type(8)));
typedef float f32x4  __attribute__((ext_vector_type(4)));

#define T_STEPS 512
#define HID     50
#define ROWS    16
#define RSTRIDE 272                        // 17 x 16B granules per m-row
#define HBUF_SZ (ROWS * RSTRIDE)           // 4352 B
#define HF_OFF  (2 * HBUF_SZ)              // 8704 B
#define ARENA_SZ (HF_OFF + ROWS * 64 * 4)  // 12800 B
#define NTHREADS 1024

#define L2E  1.442695040888963f            // log2(e)
#define L2E2 2.885390081777927f            // 2*log2(e)

// (hi bf16 in low short, lo bf16 in high short), round-to-nearest both
__device__ __forceinline__ unsigned pack_hilo(float f) {
    unsigned u  = __float_as_uint(f);
    unsigned hi = (u + 0x7fffu + ((u >> 16) & 1u)) >> 16;
    float    fh = __uint_as_float(hi << 16);
    float    rl = f - fh;
    unsigned ul = __float_as_uint(rl);
    unsigned lo = (ul + 0x7fffu + ((ul >> 16) & 1u)) >> 16;
    return (hi & 0xFFFFu) | (lo << 16);
}

__global__ __launch_bounds__(NTHREADS, 4) void lstm_mfma7_kernel(
    const float* __restrict__ x,     // [B,T,2]
    const float* __restrict__ W_ih,  // [200,2]
    const float* __restrict__ W_hh,  // [200,50]
    const float* __restrict__ b_ih,  // [200]
    const float* __restrict__ b_hh,  // [200]
    const float* __restrict__ W_fc,  // [3,50]
    const float* __restrict__ b_fc,  // [3]
    float* __restrict__ out)         // [B,3]
{
    __shared__ __align__(16) char arena[ARENA_SZ];

    const int tid  = threadIdx.x;
    const int lane = tid & 63;
    const int tau  = tid >> 6;         // wave id == tile id 0..15
    const int col  = lane & 15;        // C col = batch row; A row index m
    const int grp  = lane >> 4;        // k-group; C row-group = unit-in-tile
    const int b0   = blockIdx.x * ROWS;
    const bool act = (tau * 4) < HID;  // waves 0..12 own a real tile

    // ---- zero arena ----
    for (int i = tid; i < ARENA_SZ / 4; i += NTHREADS) ((int*)arena)[i] = 0;

    // ---- A-frag (weights) in regs for my tile ----
    // A[m][k], lane provides m = col: unit u = tau*4 + (m>>2), gate g = m&3.
    bf16x8 awhi[2], awlo[2];   // [kt]
    if (act) {
        const int u = tau * 4 + (col >> 2);
        const int g = col & 3;
#pragma unroll
        for (int kt = 0; kt < 2; ++kt) {
            bf16x8 H, L;
#pragma unroll
            for (int e = 0; e < 8; ++e) {
                int k = kt * 32 + grp * 8 + e;
                float v = 0.f;
                if (u < HID) {
                    int j = g * HID + u;
                    if      (k < HID)  v = W_hh[j * HID + k];
                    else if (k == 50)  v = W_ih[2 * j + 0];
                    else if (k == 51)  v = W_ih[2 * j + 1];
                    else if (k == 52)  v = b_ih[j] + b_hh[j];
                }
                unsigned p = pack_hilo(v);
                H[e] = (short)(p & 0xFFFFu);
                L[e] = (short)(p >> 16);
            }
            awhi[kt] = H;
            awlo[kt] = L;
        }
    }

    __syncthreads();   // zeroing complete

    // const-1.0 at k=52 (chunk 6, elems 4..5 b32: hi(k52)=0x3F80, hi(k53)=0),
    // both buffers; lo plane stays zero.
    if (tid < 2 * ROWS) {
        int buf = tid >> 4, m = tid & 15;
        *(unsigned*)(arena + buf * HBUF_SZ + m * RSTRIDE + 6 * 32 + 4 * 2) = 0x00003F80u;
    }
    // x writer: wave 13 (pad tile), lanes 0..31 -> (m 0..15) x (comp 0..1)
    const int  xm = lane & 15;
    const int  xw = (lane >> 4) & 1;
    const bool xwriter = (tau == 13) && (lane < 32);
    const float* xptr = x + (size_t)(b0 + xm) * (T_STEPS * 2) + xw;
    if (xwriter) {   // x(t=0) into buffer 0: k=50+xw -> chunk 6, elem 2+xw
        unsigned p = pack_hilo(xptr[0]);
        char* cell = arena + xm * RSTRIDE + 6 * 32 + (2 + xw) * 2;
        *(short*)cell        = (short)(p & 0xFFFFu);
        *(short*)(cell + 16) = (short)(p >> 16);
    }
    float xpre = xwriter ? xptr[1 * 2] : 0.f;   // x(t=1) in reg

    float creg = 0.f;    // cell state for my one cell
    float hreg = 0.f;

    __syncthreads();

    int pb = 0;
    for (int t = 0; t < T_STEPS; ++t) {
        char* db = arena + (pb ^ 1) * HBUF_SZ;

        // ---- x-writer FIRST: write x(t+1) into db (last read at t-1, safe),
        //      then issue x(t+2) load -> full-body shadow before the drain.
        if (xwriter) {
            unsigned p = pack_hilo(xpre);
            char* cell = db + xm * RSTRIDE + 6 * 32 + (2 + xw) * 2;
            *(short*)cell        = (short)(p & 0xFFFFu);
            *(short*)(cell + 16) = (short)(p >> 16);
            int t2 = (t + 2 < T_STEPS) ? t + 2 : T_STEPS - 1;
            xpre = xptr[(size_t)t2 * 2];   // global load issued HERE
        }

        if (act) {
            // ---- B-frags (h/x/1.0): 4 raw ds_read_b128, col = batch ----
            const char* hb = arena + pb * HBUF_SZ + col * RSTRIDE;
            bf16x8 bh[2], bl[2];
#pragma unroll
            for (int kt = 0; kt < 2; ++kt) {
                const char* p = hb + (kt * 4 + grp) * 32;
                bh[kt] = *(const bf16x8*)p;
                bl[kt] = *(const bf16x8*)(p + 16);
            }

            // ---- 6 MFMA, three independent 2-chains ----
            f32x4 a0 = {0.f, 0.f, 0.f, 0.f};
            f32x4 a1 = {0.f, 0.f, 0.f, 0.f};
            f32x4 a2 = {0.f, 0.f, 0.f, 0.f};
            a0 = __builtin_amdgcn_mfma_f32_16x16x32_bf16(awhi[0], bh[0], a0, 0, 0, 0);
            a1 = __builtin_amdgcn_mfma_f32_16x16x32_bf16(awhi[1], bh[1], a1, 0, 0, 0);
            a2 = __builtin_amdgcn_mfma_f32_16x16x32_bf16(awhi[0], bl[0], a2, 0, 0, 0);
            a0 = __builtin_amdgcn_mfma_f32_16x16x32_bf16(awlo[0], bh[0], a0, 0, 0, 0);
            a1 = __builtin_amdgcn_mfma_f32_16x16x32_bf16(awlo[1], bh[1], a1, 0, 0, 0);
            a2 = __builtin_amdgcn_mfma_f32_16x16x32_bf16(awhi[1], bl[1], a2, 0, 0, 0);
            f32x4 acc = (a0 + a1) + a2;

            // ---- epilogue: ONE cell (batch=col, unit=tau*4+grp) ----
            const int u = tau * 4 + grp;
            float pi = acc[0], pf = acc[1], pg = acc[2], po = acc[3];
            float ei = __builtin_amdgcn_exp2f(-L2E  * pi);
            float ef = __builtin_amdgcn_exp2f(-L2E  * pf);
            float eg = __builtin_amdgcn_exp2f( L2E2 * pg);
            float eo = __builtin_amdgcn_exp2f(-L2E  * po);
            float sf    = __builtin_amdgcn_rcpf(1.0f + ef);
            float ig_tg = (eg - 1.0f) * __builtin_amdgcn_rcpf((1.0f + ei) * (eg + 1.0f));
            float c = sf * creg + ig_tg;
            c = fminf(fmaxf(c, -32.0f), 32.0f);       // keep exp2 finite
            creg = c;
            float ec = __builtin_amdgcn_exp2f(L2E2 * c);
            float h  = (ec - 1.0f) * __builtin_amdgcn_rcpf((1.0f + eo) * (ec + 1.0f));
            hreg = h;
            if (u < HID) {                            // skip pad units
                unsigned p = pack_hilo(h);
                char* cell = db + col * RSTRIDE + (u >> 3) * 32 + (u & 7) * 2;
                *(short*)cell        = (short)(p & 0xFFFFu);
                *(short*)(cell + 16) = (short)(p >> 16);
            }
        }

        pb ^= 1;
        __syncthreads();
    }

    // ---- final FC: gather fp32 h, 48 threads compute out ----
    float* hf = (float*)(arena + HF_OFF);   // [16][64]
    if (act) {
        const int u = tau * 4 + grp;
        if (u < HID) hf[col * 64 + u] = hreg;
    }
    __syncthreads();
    if (tid < ROWS * 3) {
        int m = tid / 3, o = tid - m * 3;
        float s = b_fc[o];
        for (int k = 0; k < HID; ++k)
            s += hf[m * 64 + k] * W_fc[o * HID + k];
        out[(size_t)(b0 + m) * 3 + o] = s;
    }
}

extern "C" void kernel_launch(void* const* d_in, const int* in_sizes, int n_in,
                              void* d_out, int out_size, void* d_ws, size_t ws_size,
                              hipStream_t stream) {
    const float* x    = (const float*)d_in[0];
    const float* W_ih = (const float*)d_in[1];
    const float* W_hh = (const float*)d_in[2];
    const float* b_ih = (const float*)d_in[3];
    const float* b_hh = (const float*)d_in[4];
    const float* W_fc = (const float*)d_in[5];
    const float* b_fc = (const float*)d_in[6];
    float* out = (float*)d_out;

    dim3 grid(4096 / ROWS);   // 256 blocks -> 1 per CU
    dim3 block(NTHREADS);     // 16 waves -> 4 per SIMD
    lstm_mfma7_kernel<<<grid, block, 0, stream>>>(x, W_ih, W_hh, b_ih, b_hh,
                                                  W_fc, b_fc, out);
}